// Round 5
// baseline (764.422 us; speedup 1.0000x reference)
//
#include <hip/hip_runtime.h>
#include <hip/hip_cooperative_groups.h>
#include <math.h>

namespace cg = cooperative_groups;

#define Dn 1024
#define Fn 256
#define Sn 4096
#define Bn 4
#define Mn (Bn*Sn)          // 16384 rows
#define CHn 8               // scan chunk length: 2048 chunks, wave/chunk
#define NCn (Sn/CHn)        // 512 chunks per sequence

typedef __bf16 bf16x8 __attribute__((ext_vector_type(8)));
typedef float  f32x4  __attribute__((ext_vector_type(4)));

__device__ inline unsigned short f2bf(float f) {
  unsigned int u = __float_as_uint(f);
  u += 0x7fffu + ((u >> 16) & 1u);
  return (unsigned short)(u >> 16);
}
__device__ inline float bf2f(unsigned short s) {
  return __uint_as_float(((unsigned int)s) << 16);
}

__device__ inline void async16(const void* g, void* l) {
  __builtin_amdgcn_global_load_lds(
      (__attribute__((address_space(1))) void*)(g),
      (__attribute__((address_space(3))) void*)(l), 16, 0, 0);
}

// wait until at most n vector-memory ops outstanding; don't touch lgkm/exp
#define WAITVM(n) __builtin_amdgcn_s_waitcnt(0xF70 | (n))
// raw barrier with memory clobber: no compiler-inserted vmcnt(0) drain
#define BARRIER() asm volatile("s_barrier" ::: "memory")

// ---------------- LN1 (f32->bf16, wave-per-row) + weight conv + errAcc=0 ---
__global__ __launch_bounds__(256) void ln1_conv(
    const float* __restrict__ x, const float* __restrict__ g,
    const float* __restrict__ b, unsigned short* __restrict__ out,
    const float* __restrict__ wspec, const float* __restrict__ wfrom,
    const float* __restrict__ w1, const float* __restrict__ w2,
    unsigned short* __restrict__ o_spec, unsigned short* __restrict__ o_from,
    unsigned short* __restrict__ o_w1, unsigned short* __restrict__ o_w2,
    float* __restrict__ errAcc) {
  int tid = threadIdx.x;
  int gid = blockIdx.x * 256 + tid;     // 0..1048575
  if (gid == 0) errAcc[0] = 0.0f;       // replaces hipMemsetAsync (1 dispatch)
  o_w1[gid] = f2bf(w1[gid]);
  o_w2[gid] = f2bf(w2[gid]);
  if (gid < 524288) {
    o_spec[gid] = f2bf(wspec[gid]);
    o_from[gid] = f2bf(wfrom[gid]);
  }

  int wid = tid >> 6, lane = tid & 63;
  int row = blockIdx.x * 4 + wid;
  const float4* xr = (const float4*)x + (size_t)row * 256;
  float4 v[4];
  float s = 0.0f, ss = 0.0f;
  #pragma unroll
  for (int k = 0; k < 4; k++) {
    v[k] = xr[lane + 64 * k];
    s  += v[k].x + v[k].y + v[k].z + v[k].w;
    ss += v[k].x * v[k].x + v[k].y * v[k].y + v[k].z * v[k].z + v[k].w * v[k].w;
  }
  #pragma unroll
  for (int o = 32; o; o >>= 1) {
    s  += __shfl_xor(s, o);
    ss += __shfl_xor(ss, o);
  }
  float mu  = s * (1.0f / Dn);
  float var = ss * (1.0f / Dn) - mu * mu;
  float rs  = rsqrtf(var + 1e-5f);
  ushort4* orow = (ushort4*)out + (size_t)row * 256;
  #pragma unroll
  for (int k = 0; k < 4; k++) {
    float4 gv = ((const float4*)g)[lane + 64 * k];
    float4 bv = ((const float4*)b)[lane + 64 * k];
    ushort4 w;
    w.x = f2bf((v[k].x - mu) * rs * gv.x + bv.x);
    w.y = f2bf((v[k].y - mu) * rs * gv.y + bv.y);
    w.z = f2bf((v[k].z - mu) * rs * gv.z + bv.z);
    w.w = f2bf((v[k].w - mu) * rs * gv.w + bv.w);
    orow[lane + 64 * k] = w;
  }
}

// ---------------- LN2 (bf16->f32, wave-per-row) + finalize_err -------------
__global__ __launch_bounds__(256) void ln2_err(
    const unsigned short* __restrict__ h, const float* __restrict__ g,
    const float* __restrict__ b, float* __restrict__ out,
    const float* __restrict__ errAcc, float* __restrict__ outErr) {
  int tid = threadIdx.x;
  if (blockIdx.x == 0 && tid == 0) {
    float m = errAcc[0] * (1.0f / 16777216.0f);   // / (Mn*Dn)
    outErr[0] = fminf(fmaxf(m, 0.0f), 1.0f);
  }
  int wid = tid >> 6, lane = tid & 63;
  int row = blockIdx.x * 4 + wid;
  const ushort4* xr = (const ushort4*)h + (size_t)row * 256;
  float4 v[4];
  float s = 0.0f, ss = 0.0f;
  #pragma unroll
  for (int k = 0; k < 4; k++) {
    ushort4 u = xr[lane + 64 * k];
    v[k].x = bf2f(u.x); v[k].y = bf2f(u.y); v[k].z = bf2f(u.z); v[k].w = bf2f(u.w);
    s  += v[k].x + v[k].y + v[k].z + v[k].w;
    ss += v[k].x * v[k].x + v[k].y * v[k].y + v[k].z * v[k].z + v[k].w * v[k].w;
  }
  #pragma unroll
  for (int o = 32; o; o >>= 1) {
    s  += __shfl_xor(s, o);
    ss += __shfl_xor(ss, o);
  }
  float mu  = s * (1.0f / Dn);
  float var = ss * (1.0f / Dn) - mu * mu;
  float rs  = rsqrtf(var + 1e-5f);
  float4* orow = (float4*)out + (size_t)row * 256;
  #pragma unroll
  for (int k = 0; k < 4; k++) {
    float4 gv = ((const float4*)g)[lane + 64 * k];
    float4 bv = ((const float4*)b)[lane + 64 * k];
    float4 w;
    w.x = (v[k].x - mu) * rs * gv.x + bv.x;
    w.y = (v[k].y - mu) * rs * gv.y + bv.y;
    w.z = (v[k].z - mu) * rs * gv.z + bv.z;
    w.w = (v[k].w - mu) * rs * gv.w + bv.w;
    orow[lane + 64 * k] = w;
  }
}

// ---------------- 128x128 MFMA GEMM (all four GEMMs) -----------------------
// 4 blocks/CU: inter-block overlap hides the per-K-iter barrier drain (m114)
// and the epilogue's global traffic. At K=512/1024 (16-32 K-iters) this beats
// the 256^2 8-phase template (confirmed R3->R4: -19us).
template <int MODE>
__global__ __launch_bounds__(256, 4) void gemm_bt(
    const unsigned short* __restrict__ A, const unsigned short* __restrict__ Bw,
    int K, int N,
    float* __restrict__ outF, unsigned short* __restrict__ outH,
    const float* __restrict__ td, const float* __restrict__ bias,
    const float* __restrict__ ew, float* __restrict__ errAcc) {
  __shared__ unsigned short As[2 * 4096];
  __shared__ unsigned short Bs[2 * 4096];
  __shared__ float red[4];

  int tid = threadIdx.x;
  int wid = tid >> 6, lane = tid & 63;
  int wm = wid >> 1, wn = wid & 1;
  int quad = lane >> 4, l16 = lane & 15;

  int g = blockIdx.x + gridDim.x * blockIdx.y;
  int nbn = gridDim.x;
  int gh = g >> 3;
  int bn = gh % nbn;
  int bm = (g & 7) + (gh / nbn) * 8;

  int r_lo = lane >> 2;
  int c8   = (lane & 3) * 8;

  const unsigned short* Abase = A + (size_t)bm * 128 * K;
  const unsigned short* Bbase = Bw + (size_t)bn * 128 * K;

  f32x4 acc[4][4] = {};

  const int T = K >> 5;
  auto issue = [&](int t, int stg) {
    int k0 = t << 5;
    #pragma unroll
    for (int s = 0; s < 2; ++s) {
      int chunk = s * 4 + wid;
      int r = chunk * 16 + r_lo;
      async16(Abase + (size_t)r * K + k0 + c8, As + stg * 4096 + chunk * 512);
      async16(Bbase + (size_t)r * K + k0 + c8, Bs + stg * 4096 + chunk * 512);
    }
  };

  issue(0, 0);

  for (int k = 0; k < T; ++k) {
    WAITVM(0);
    BARRIER();
    if (k + 1 < T) issue(k + 1, (k + 1) & 1);

    const unsigned short* Ab = As + (k & 1) * 4096;
    const unsigned short* Bb = Bs + (k & 1) * 4096;
    bf16x8 af[4], bf[4];
    #pragma unroll
    for (int i = 0; i < 4; i++)
      af[i] = *(const bf16x8*)(Ab + (wm * 64 + i * 16 + l16) * 32 + quad * 8);
    #pragma unroll
    for (int j = 0; j < 4; j++)
      bf[j] = *(const bf16x8*)(Bb + (wn * 64 + j * 16 + l16) * 32 + quad * 8);
    #pragma unroll
    for (int i = 0; i < 4; i++)
      #pragma unroll
      for (int j = 0; j < 4; j++)
        acc[i][j] = __builtin_amdgcn_mfma_f32_16x16x32_bf16(af[i], bf[j], acc[i][j], 0, 0, 0);
  }

  float esum = 0.0f;
  float sigw = 0.0f;
  if (MODE == 1) sigw = 1.0f / (1.0f + expf(-ew[0]));

  #pragma unroll
  for (int i = 0; i < 4; i++) {
    int row_base = bm * 128 + wm * 64 + i * 16 + quad * 4;
    #pragma unroll
    for (int j = 0; j < 4; j++) {
      int col = bn * 128 + wn * 64 + j * 16 + l16;
      #pragma unroll
      for (int r = 0; r < 4; r++) {
        size_t idx = (size_t)(row_base + r) * N + col;
        float v = acc[i][j][r];
        if (MODE == 0) {
          outH[idx] = f2bf(v);
        } else if (MODE == 1) {
          float e = v - td[idx];
          e = fminf(fmaxf(e, -1.0f), 1.0f);
          float corr = v - sigw * e;
          outF[idx] = corr;
          outH[idx] = f2bf(corr);
          esum += e * e;
        } else if (MODE == 2) {
          float h = v + bias[col];
          float gel = 0.5f * h * (1.0f + erff(h * 0.70710678118654752f));
          outH[idx] = f2bf(gel);
        } else if (MODE == 3) {
          outF[idx] = v + bias[col];
        } else {
          outH[idx] = f2bf(v + bias[col]);
        }
      }
    }
  }

  if (MODE == 1) {
    #pragma unroll
    for (int o = 32; o; o >>= 1) esum += __shfl_down(esum, o);
    if (lane == 0) red[wid] = esum;
    __syncthreads();
    if (tid == 0) atomicAdd(errAcc, red[0] + red[1] + red[2] + red[3]);
  }
}

// ---------------- fused scan (cooperative, 512 blocks x 256 threads) -------
// Phase 1: wave-per-chunk partial scan, raw u kept in 32 VGPRs.
// Phase 2: per-(b,f) carry scan: 4-serial segment + Kogge-Stone(128) in LDS.
// Phase 3: O(1) carry + 8-step scan + rotate from the reg-held u; spec is
// read exactly ONCE.  grid.sync() + __threadfence() for cross-XCD handoff.
__global__ __launch_bounds__(256) void scan_fused(
    const unsigned short* __restrict__ spec, const float* __restrict__ log_decay,
    const float* __restrict__ freq, float2* __restrict__ chunkfin,
    float2* __restrict__ carries, unsigned short* __restrict__ outH) {
  cg::grid_group grid = cg::this_grid();
  __shared__ float2 ks[2][128];

  int tid = threadIdx.x, wid = tid >> 6, lane = tid & 63;
  int chunk = blockIdx.x * 4 + wid;       // 0..2047
  int b = chunk >> 9, c = chunk & (NCn - 1);
  int f0 = lane * 4;

  // ---- phase 1: partial scan, keep u in registers
  ushort4 ur[CHn], ui[CHn];
  const unsigned short* u = spec + ((size_t)b * Sn + (size_t)c * CHn) * 512;
  #pragma unroll
  for (int t = 0; t < CHn; t++) {
    ur[t] = *(const ushort4*)(u + (size_t)t * 512 + f0);
    ui[t] = *(const ushort4*)(u + (size_t)t * 512 + 256 + f0);
  }
  float Are[4], Aim[4], Rre[4], Rim[4];
  #pragma unroll
  for (int k = 0; k < 4; k++) {
    float dec = 1.0f / (1.0f + expf(-log_decay[f0 + k]));
    float om  = tanhf(freq[f0 + k]) * 0.1f;
    Rre[k] = cosf(om); Rim[k] = sinf(om);
    Are[k] = dec * Rre[k]; Aim[k] = dec * Rim[k];
  }
  {
    float sre[4] = {0, 0, 0, 0}, sim[4] = {0, 0, 0, 0};
    #pragma unroll
    for (int t = 0; t < CHn; t++) {
      const unsigned short* urp = &ur[t].x;
      const unsigned short* uip = &ui[t].x;
      #pragma unroll
      for (int k = 0; k < 4; k++) {
        float nre = Are[k] * sre[k] - Aim[k] * sim[k] + bf2f(urp[k]);
        float nim = Are[k] * sim[k] + Aim[k] * sre[k] + bf2f(uip[k]);
        sre[k] = nre; sim[k] = nim;
      }
    }
    #pragma unroll
    for (int k = 0; k < 4; k++)
      chunkfin[((size_t)(b * 256 + f0 + k)) * NCn + c] = make_float2(sre[k], sim[k]);
  }
  __threadfence();
  grid.sync();
  __threadfence();

  // ---- phase 2: carry scan. pair = (b,f); block handles 2 pairs.
  {
    int half = tid >> 7;                 // 0,1
    int pair = blockIdx.x * 2 + half;    // 0..1023
    int h = tid & 127;                   // segment index (4 chunks each)
    int fb = pair & 255, pb = pair >> 8;
    float dec = 1.0f / (1.0f + expf(-log_decay[fb]));
    float om  = tanhf(freq[fb]) * 0.1f;
    float Pre = dec * cosf(om), Pim = dec * sinf(om);
    #pragma unroll
    for (int i = 0; i < 3; i++) {        // P = A^CHn (CHn=8)
      float nr = Pre * Pre - Pim * Pim, ni = 2.0f * Pre * Pim;
      Pre = nr; Pim = ni;
    }
    const float2* cfb = chunkfin + (size_t)(pb * 256 + fb) * NCn + h * 4;
    float2 cf0 = cfb[0], cf1 = cfb[1], cf2 = cfb[2], cf3 = cfb[3];
    // segment combine: S = P^3 cf0 + P^2 cf1 + P cf2 + cf3
    float2 S = cf0;
    { float nx = Pre*S.x - Pim*S.y + cf1.x, ny = Pre*S.y + Pim*S.x + cf1.y; S.x=nx; S.y=ny; }
    { float nx = Pre*S.x - Pim*S.y + cf2.x, ny = Pre*S.y + Pim*S.x + cf2.y; S.x=nx; S.y=ny; }
    { float nx = Pre*S.x - Pim*S.y + cf3.x, ny = Pre*S.y + Pim*S.x + cf3.y; S.x=nx; S.y=ny; }
    // KS over 128 segments, multiplier Q = P^4
    float Mre = Pre, Mim = Pim;
    #pragma unroll
    for (int i = 0; i < 2; i++) {
      float nr = Mre * Mre - Mim * Mim, ni = 2.0f * Mre * Mim;
      Mre = nr; Mim = ni;
    }
    ks[half][h] = S;
    __syncthreads();
    float2 v = S;
    for (int s = 1; s < 128; s <<= 1) {
      float2 w = (h >= s) ? ks[half][h - s] : make_float2(0.0f, 0.0f);
      __syncthreads();
      v.x += Mre * w.x - Mim * w.y;
      v.y += Mre * w.y + Mim * w.x;
      ks[half][h] = v;
      __syncthreads();
      float nr = Mre * Mre - Mim * Mim, ni = 2.0f * Mre * Mim;
      Mre = nr; Mim = ni;
    }
    float2 e = (h == 0) ? make_float2(0.0f, 0.0f) : ks[half][h - 1];
    // walk the 4 chunks of the segment, writing exclusive carries
    float2* cw = carries + (size_t)(pb * 256 + fb) * NCn + h * 4;
    cw[0] = e;
    { float nx = Pre*e.x - Pim*e.y + cf0.x, ny = Pre*e.y + Pim*e.x + cf0.y; e.x=nx; e.y=ny; }
    cw[1] = e;
    { float nx = Pre*e.x - Pim*e.y + cf1.x, ny = Pre*e.y + Pim*e.x + cf1.y; e.x=nx; e.y=ny; }
    cw[2] = e;
    { float nx = Pre*e.x - Pim*e.y + cf2.x, ny = Pre*e.y + Pim*e.x + cf2.y; e.x=nx; e.y=ny; }
    cw[3] = e;
  }
  __threadfence();
  grid.sync();
  __threadfence();

  // ---- phase 3: final scan + rotate from reg-held u
  {
    float sre[4], sim[4];
    #pragma unroll
    for (int k = 0; k < 4; k++) {
      float2 s0 = carries[((size_t)(b * 256 + f0 + k)) * NCn + c];
      sre[k] = s0.x; sim[k] = s0.y;
    }
    unsigned short* o = outH + ((size_t)b * Sn + (size_t)c * CHn) * 512;
    #pragma unroll
    for (int t = 0; t < CHn; t++) {
      const unsigned short* urp = &ur[t].x;
      const unsigned short* uip = &ui[t].x;
      ushort4 wr, wi;
      unsigned short* wrp = &wr.x;
      unsigned short* wip = &wi.x;
      #pragma unroll
      for (int k = 0; k < 4; k++) {
        float nre = Are[k] * sre[k] - Aim[k] * sim[k] + bf2f(urp[k]);
        float nim = Are[k] * sim[k] + Aim[k] * sre[k] + bf2f(uip[k]);
        sre[k] = nre; sim[k] = nim;
        wrp[k] = f2bf(Rre[k] * sre[k] - Rim[k] * sim[k]);
        wip[k] = f2bf(Rre[k] * sim[k] + Rim[k] * sre[k]);
      }
      *(ushort4*)(o + (size_t)t * 512 + f0) = wr;
      *(ushort4*)(o + (size_t)t * 512 + 256 + f0) = wi;
    }
  }
}

// ---------------------------------------------------------------------------
extern "C" void kernel_launch(void* const* d_in, const int* in_sizes, int n_in,
                              void* d_out, int out_size, void* d_ws, size_t ws_size,
                              hipStream_t stream) {
  (void)in_sizes; (void)n_in; (void)out_size; (void)ws_size;
  const float* x     = (const float*)d_in[0];
  const float* td    = (const float*)d_in[1];
  const float* wspec = (const float*)d_in[2];
  const float* logd  = (const float*)d_in[3];
  const float* freq  = (const float*)d_in[4];
  const float* wfrom = (const float*)d_in[5];
  const float* g1    = (const float*)d_in[6];
  const float* b1ln  = (const float*)d_in[7];
  const float* W1    = (const float*)d_in[8];
  const float* b1    = (const float*)d_in[9];
  const float* W2    = (const float*)d_in[10];
  const float* b2    = (const float*)d_in[11];
  const float* g2    = (const float*)d_in[12];
  const float* b2ln  = (const float*)d_in[13];
  const float* ew    = (const float*)d_in[14];

  char* ws = (char*)d_ws;
  size_t off = 0;
  float* errAcc = (float*)(ws + off);              off += 256;
  unsigned short* wspec_h = (unsigned short*)(ws + off); off += (size_t)512 * 1024 * 2;
  unsigned short* wfrom_h = (unsigned short*)(ws + off); off += (size_t)1024 * 512 * 2;
  unsigned short* w1_h    = (unsigned short*)(ws + off); off += (size_t)1024 * 1024 * 2;
  unsigned short* w2_h    = (unsigned short*)(ws + off); off += (size_t)1024 * 1024 * 2;
  // region A (32MB): xn_h [LN1->G0] -> corr_h [G1->G2] -> h2_h [G3->LN2]
  unsigned short* xn_h   = (unsigned short*)(ws + off);
  unsigned short* corr_h = (unsigned short*)(ws + off);
  unsigned short* h2_h   = (unsigned short*)(ws + off); off += (size_t)Mn * 1024 * 2;
  // region B (32MB): spec bf16 [G0->scan] -> h1_h [G2->G3]
  unsigned short* spec  = (unsigned short*)(ws + off);
  unsigned short* h1_h  = (unsigned short*)(ws + off);  off += (size_t)Mn * 1024 * 2;
  // region C (16MB): so_h [scan->G1]
  unsigned short* so_h = (unsigned short*)(ws + off);  off += (size_t)Mn * 512 * 2;
  float2* chunkfin = (float2*)(ws + off);              off += (size_t)Bn * 256 * NCn * 8;
  float2* carries  = (float2*)(ws + off);              off += (size_t)Bn * 256 * NCn * 8;

  float* outCorr = (float*)d_out;
  float* outNP   = outCorr + (size_t)Mn * 1024;
  float* outErr  = outNP + (size_t)Mn * 1024;

  // LN1 + all weight converts + errAcc zero (1M threads, exact cover)
  ln1_conv<<<4096, 256, 0, stream>>>(x, g1, b1ln, xn_h,
                                     wspec, wfrom, W1, W2,
                                     wspec_h, wfrom_h, w1_h, w2_h, errAcc);
  // G0: spectral = xn @ W_spec^T : [16384,1024] x [512,1024]^T -> bf16
  gemm_bt<0><<<dim3(512 / 128, Mn / 128), 256, 0, stream>>>(
      xn_h, wspec_h, 1024, 512, nullptr, spec, nullptr, nullptr, nullptr, nullptr);
  // fused cooperative scan (3 dispatches -> 1; spec read once)
  {
    const unsigned short* specc = spec;
    void* kargs[] = {(void*)&specc, (void*)&logd, (void*)&freq,
                     (void*)&chunkfin, (void*)&carries, (void*)&so_h};
    hipLaunchCooperativeKernel((void*)scan_fused, dim3(512), dim3(256),
                               kargs, 0, stream);
  }
  // G1: bu = so @ W_from^T, fused error/corrected + err^2 reduce
  gemm_bt<1><<<dim3(1024 / 128, Mn / 128), 256, 0, stream>>>(
      so_h, wfrom_h, 512, 1024, outCorr, corr_h, td, nullptr, ew, errAcc);
  // G2: h1 = gelu(corr @ W1^T + b1)
  gemm_bt<2><<<dim3(1024 / 128, Mn / 128), 256, 0, stream>>>(
      corr_h, w1_h, 1024, 1024, nullptr, h1_h, nullptr, b1, nullptr, nullptr);
  // G3: h2 = bf16(h1 @ W2^T + b2)
  gemm_bt<4><<<dim3(1024 / 128, Mn / 128), 256, 0, stream>>>(
      h1_h, w2_h, 1024, 1024, nullptr, h2_h, nullptr, b2, nullptr, nullptr);
  // LN2 (bf16 -> f32 into d_out) + finalize_err
  ln2_err<<<4096, 256, 0, stream>>>(h2_h, g2, b2ln, outNP, errAcc, outErr);
}

// Round 7
// 445.094 us; speedup vs baseline: 1.7174x; 1.7174x over previous
//
#include <hip/hip_runtime.h>
#include <math.h>

#define Dn 1024
#define Fn 256
#define Sn 4096
#define Bn 4
#define Mn (Bn*Sn)          // 16384 rows
#define CHn 8               // scan chunk length: 2048 chunks, wave/chunk
#define NCn (Sn/CHn)        // 512 chunks per sequence

typedef __bf16 bf16x8 __attribute__((ext_vector_type(8)));
typedef float  f32x4  __attribute__((ext_vector_type(4)));

__device__ inline unsigned short f2bf(float f) {
  unsigned int u = __float_as_uint(f);
  u += 0x7fffu + ((u >> 16) & 1u);
  return (unsigned short)(u >> 16);
}
__device__ inline float bf2f(unsigned short s) {
  return __uint_as_float(((unsigned int)s) << 16);
}

__device__ inline void async16(const void* g, void* l) {
  __builtin_amdgcn_global_load_lds(
      (__attribute__((address_space(1))) void*)(g),
      (__attribute__((address_space(3))) void*)(l), 16, 0, 0);
}

// wait until at most n vector-memory ops outstanding; don't touch lgkm/exp
#define WAITVM(n) __builtin_amdgcn_s_waitcnt(0xF70 | (n))
// raw barrier with memory clobber: no compiler-inserted vmcnt(0) drain
#define BARRIER() asm volatile("s_barrier" ::: "memory")

// ---------------- LN1 (f32->bf16, wave-per-row) + weight conv + errAcc=0 ---
__global__ __launch_bounds__(256) void ln1_conv(
    const float* __restrict__ x, const float* __restrict__ g,
    const float* __restrict__ b, unsigned short* __restrict__ out,
    const float* __restrict__ wspec, const float* __restrict__ wfrom,
    const float* __restrict__ w1, const float* __restrict__ w2,
    unsigned short* __restrict__ o_spec, unsigned short* __restrict__ o_from,
    unsigned short* __restrict__ o_w1, unsigned short* __restrict__ o_w2,
    float* __restrict__ errAcc) {
  int tid = threadIdx.x;
  int gid = blockIdx.x * 256 + tid;     // 0..1048575
  if (gid == 0) errAcc[0] = 0.0f;       // replaces hipMemsetAsync (1 dispatch)
  o_w1[gid] = f2bf(w1[gid]);
  o_w2[gid] = f2bf(w2[gid]);
  if (gid < 524288) {
    o_spec[gid] = f2bf(wspec[gid]);
    o_from[gid] = f2bf(wfrom[gid]);
  }

  int wid = tid >> 6, lane = tid & 63;
  int row = blockIdx.x * 4 + wid;
  const float4* xr = (const float4*)x + (size_t)row * 256;
  float4 v[4];
  float s = 0.0f, ss = 0.0f;
  #pragma unroll
  for (int k = 0; k < 4; k++) {
    v[k] = xr[lane + 64 * k];
    s  += v[k].x + v[k].y + v[k].z + v[k].w;
    ss += v[k].x * v[k].x + v[k].y * v[k].y + v[k].z * v[k].z + v[k].w * v[k].w;
  }
  #pragma unroll
  for (int o = 32; o; o >>= 1) {
    s  += __shfl_xor(s, o);
    ss += __shfl_xor(ss, o);
  }
  float mu  = s * (1.0f / Dn);
  float var = ss * (1.0f / Dn) - mu * mu;
  float rs  = rsqrtf(var + 1e-5f);
  ushort4* orow = (ushort4*)out + (size_t)row * 256;
  #pragma unroll
  for (int k = 0; k < 4; k++) {
    float4 gv = ((const float4*)g)[lane + 64 * k];
    float4 bv = ((const float4*)b)[lane + 64 * k];
    ushort4 w;
    w.x = f2bf((v[k].x - mu) * rs * gv.x + bv.x);
    w.y = f2bf((v[k].y - mu) * rs * gv.y + bv.y);
    w.z = f2bf((v[k].z - mu) * rs * gv.z + bv.z);
    w.w = f2bf((v[k].w - mu) * rs * gv.w + bv.w);
    orow[lane + 64 * k] = w;
  }
}

// ---------------- LN2 (bf16->f32, wave-per-row) + finalize_err -------------
__global__ __launch_bounds__(256) void ln2_err(
    const unsigned short* __restrict__ h, const float* __restrict__ g,
    const float* __restrict__ b, float* __restrict__ out,
    const float* __restrict__ errAcc, float* __restrict__ outErr) {
  int tid = threadIdx.x;
  if (blockIdx.x == 0 && tid == 0) {
    float m = errAcc[0] * (1.0f / 16777216.0f);   // / (Mn*Dn)
    outErr[0] = fminf(fmaxf(m, 0.0f), 1.0f);
  }
  int wid = tid >> 6, lane = tid & 63;
  int row = blockIdx.x * 4 + wid;
  const ushort4* xr = (const ushort4*)h + (size_t)row * 256;
  float4 v[4];
  float s = 0.0f, ss = 0.0f;
  #pragma unroll
  for (int k = 0; k < 4; k++) {
    ushort4 u = xr[lane + 64 * k];
    v[k].x = bf2f(u.x); v[k].y = bf2f(u.y); v[k].z = bf2f(u.z); v[k].w = bf2f(u.w);
    s  += v[k].x + v[k].y + v[k].z + v[k].w;
    ss += v[k].x * v[k].x + v[k].y * v[k].y + v[k].z * v[k].z + v[k].w * v[k].w;
  }
  #pragma unroll
  for (int o = 32; o; o >>= 1) {
    s  += __shfl_xor(s, o);
    ss += __shfl_xor(ss, o);
  }
  float mu  = s * (1.0f / Dn);
  float var = ss * (1.0f / Dn) - mu * mu;
  float rs  = rsqrtf(var + 1e-5f);
  f32x4* orow = (f32x4*)out + (size_t)row * 256;
  #pragma unroll
  for (int k = 0; k < 4; k++) {
    float4 gv = ((const float4*)g)[lane + 64 * k];
    float4 bv = ((const float4*)b)[lane + 64 * k];
    f32x4 w;
    w[0] = (v[k].x - mu) * rs * gv.x + bv.x;
    w[1] = (v[k].y - mu) * rs * gv.y + bv.y;
    w[2] = (v[k].z - mu) * rs * gv.z + bv.z;
    w[3] = (v[k].w - mu) * rs * gv.w + bv.w;
    __builtin_nontemporal_store(w, &orow[lane + 64 * k]);   // streaming output
  }
}

// ---------------- 128x128 MFMA GEMM (all four GEMMs) -----------------------
// 4 blocks/CU: inter-block overlap hides the per-K-iter barrier drain (m114)
// and the epilogue's global traffic. At K=512/1024 (16-32 K-iters) this beats
// the 256^2 8-phase template (confirmed R3->R4: -19us).
template <int MODE>
__global__ __launch_bounds__(256, 4) void gemm_bt(
    const unsigned short* __restrict__ A, const unsigned short* __restrict__ Bw,
    int K, int N,
    float* __restrict__ outF, unsigned short* __restrict__ outH,
    const float* __restrict__ td, const float* __restrict__ bias,
    const float* __restrict__ ew, float* __restrict__ errAcc) {
  __shared__ unsigned short As[2 * 4096];
  __shared__ unsigned short Bs[2 * 4096];
  __shared__ float red[4];

  int tid = threadIdx.x;
  int wid = tid >> 6, lane = tid & 63;
  int wm = wid >> 1, wn = wid & 1;
  int quad = lane >> 4, l16 = lane & 15;

  int g = blockIdx.x + gridDim.x * blockIdx.y;
  int nbn = gridDim.x;
  int gh = g >> 3;
  int bn = gh % nbn;
  int bm = (g & 7) + (gh / nbn) * 8;

  int r_lo = lane >> 2;
  int c8   = (lane & 3) * 8;

  const unsigned short* Abase = A + (size_t)bm * 128 * K;
  const unsigned short* Bbase = Bw + (size_t)bn * 128 * K;

  f32x4 acc[4][4] = {};

  const int T = K >> 5;
  auto issue = [&](int t, int stg) {
    int k0 = t << 5;
    #pragma unroll
    for (int s = 0; s < 2; ++s) {
      int chunk = s * 4 + wid;
      int r = chunk * 16 + r_lo;
      async16(Abase + (size_t)r * K + k0 + c8, As + stg * 4096 + chunk * 512);
      async16(Bbase + (size_t)r * K + k0 + c8, Bs + stg * 4096 + chunk * 512);
    }
  };

  issue(0, 0);

  for (int k = 0; k < T; ++k) {
    WAITVM(0);
    BARRIER();
    if (k + 1 < T) issue(k + 1, (k + 1) & 1);

    const unsigned short* Ab = As + (k & 1) * 4096;
    const unsigned short* Bb = Bs + (k & 1) * 4096;
    bf16x8 af[4], bf[4];
    #pragma unroll
    for (int i = 0; i < 4; i++)
      af[i] = *(const bf16x8*)(Ab + (wm * 64 + i * 16 + l16) * 32 + quad * 8);
    #pragma unroll
    for (int j = 0; j < 4; j++)
      bf[j] = *(const bf16x8*)(Bb + (wn * 64 + j * 16 + l16) * 32 + quad * 8);
    #pragma unroll
    for (int i = 0; i < 4; i++)
      #pragma unroll
      for (int j = 0; j < 4; j++)
        acc[i][j] = __builtin_amdgcn_mfma_f32_16x16x32_bf16(af[i], bf[j], acc[i][j], 0, 0, 0);
  }

  float esum = 0.0f;
  float sigw = 0.0f;
  if (MODE == 1) sigw = 1.0f / (1.0f + expf(-ew[0]));

  #pragma unroll
  for (int i = 0; i < 4; i++) {
    int row_base = bm * 128 + wm * 64 + i * 16 + quad * 4;
    #pragma unroll
    for (int j = 0; j < 4; j++) {
      int col = bn * 128 + wn * 64 + j * 16 + l16;
      #pragma unroll
      for (int r = 0; r < 4; r++) {
        size_t idx = (size_t)(row_base + r) * N + col;
        float v = acc[i][j][r];
        if (MODE == 0) {
          outH[idx] = f2bf(v);
        } else if (MODE == 1) {
          float e = v - __builtin_nontemporal_load(&td[idx]);  // read-once stream
          e = fminf(fmaxf(e, -1.0f), 1.0f);
          float corr = v - sigw * e;
          __builtin_nontemporal_store(corr, &outF[idx]);       // streaming output
          outH[idx] = f2bf(corr);
          esum += e * e;
        } else if (MODE == 2) {
          float h = v + bias[col];
          float gel = 0.5f * h * (1.0f + erff(h * 0.70710678118654752f));
          outH[idx] = f2bf(gel);
        } else if (MODE == 3) {
          __builtin_nontemporal_store(v + bias[col], &outF[idx]);
        } else {
          outH[idx] = f2bf(v + bias[col]);
        }
      }
    }
  }

  if (MODE == 1) {
    #pragma unroll
    for (int o = 32; o; o >>= 1) esum += __shfl_down(esum, o);
    if (lane == 0) red[wid] = esum;
    __syncthreads();
    if (tid == 0) atomicAdd(errAcc, red[0] + red[1] + red[2] + red[3]);
  }
}

// ---------------- scans ----------------------------------------------------
// chunkfin/carries layout: [b][f][c] float2  (c contiguous -> coalesced carry)
// scan_partial: wave-per-chunk, lane owns 4 freqs (ushort4 loads), chain = 8.
__global__ __launch_bounds__(256) void scan_partial(
    const unsigned short* __restrict__ spec, const float* __restrict__ log_decay,
    const float* __restrict__ freq, float2* __restrict__ chunkfin) {
  int tid = threadIdx.x, wid = tid >> 6, lane = tid & 63;
  int chunk = blockIdx.x * 4 + wid;       // 0..2047
  int b = chunk >> 9, c = chunk & (NCn - 1);
  int f0 = lane * 4;
  float Are[4], Aim[4];
  #pragma unroll
  for (int k = 0; k < 4; k++) {
    float dec = 1.0f / (1.0f + expf(-log_decay[f0 + k]));
    float om  = tanhf(freq[f0 + k]) * 0.1f;
    Are[k] = dec * cosf(om); Aim[k] = dec * sinf(om);
  }
  const unsigned short* u = spec + ((size_t)b * Sn + (size_t)c * CHn) * 512;
  float sre[4] = {0, 0, 0, 0}, sim[4] = {0, 0, 0, 0};
  #pragma unroll
  for (int t = 0; t < CHn; t++) {
    ushort4 ur = *(const ushort4*)(u + (size_t)t * 512 + f0);
    ushort4 ui = *(const ushort4*)(u + (size_t)t * 512 + 256 + f0);
    float urf[4] = {bf2f(ur.x), bf2f(ur.y), bf2f(ur.z), bf2f(ur.w)};
    float uif[4] = {bf2f(ui.x), bf2f(ui.y), bf2f(ui.z), bf2f(ui.w)};
    #pragma unroll
    for (int k = 0; k < 4; k++) {
      float nre = Are[k] * sre[k] - Aim[k] * sim[k] + urf[k];
      float nim = Are[k] * sim[k] + Aim[k] * sre[k] + uif[k];
      sre[k] = nre; sim[k] = nim;
    }
  }
  #pragma unroll
  for (int k = 0; k < 4; k++)
    chunkfin[((size_t)(b * 256 + f0 + k)) * NCn + c] = make_float2(sre[k], sim[k]);
}

// Kogge-Stone carry scan: block = (b,f), thread = chunk c. Inclusive scan
// E[c] = chunkfin[c] + P*E[c-1] (P = A^CHn) via log-rounds in LDS; write
// exclusive prefix as the carry into chunk c. 1024 blocks x 512 thr.
__global__ __launch_bounds__(512) void scan_carry(
    const float* __restrict__ log_decay, const float* __restrict__ freq,
    const float2* __restrict__ chunkfin, float2* __restrict__ carries) {
  __shared__ float2 buf[NCn];
  int bf = blockIdx.x;              // 0..1023: b = bf>>8, f = bf&255
  int f = bf & 255;
  int c = threadIdx.x;              // 0..511
  float dec = 1.0f / (1.0f + expf(-log_decay[f]));
  float om  = tanhf(freq[f]) * 0.1f;
  float Mre = dec * cosf(om), Mim = dec * sinf(om);
  #pragma unroll
  for (int i = 0; i < 3; i++) {     // A^(2^3) = A^CHn (CHn=8)
    float nr = Mre * Mre - Mim * Mim;
    float ni = 2.0f * Mre * Mim;
    Mre = nr; Mim = ni;
  }
  float2 v = chunkfin[(size_t)bf * NCn + c];
  buf[c] = v;
  __syncthreads();
  for (int s = 1; s < NCn; s <<= 1) {
    float2 w = (c >= s) ? buf[c - s] : make_float2(0.0f, 0.0f);
    __syncthreads();
    v.x += Mre * w.x - Mim * w.y;
    v.y += Mre * w.y + Mim * w.x;
    buf[c] = v;
    __syncthreads();
    float nr = Mre * Mre - Mim * Mim;   // M = M^2 (next stride)
    float ni = 2.0f * Mre * Mim;
    Mre = nr; Mim = ni;
  }
  float2 e = (c == 0) ? make_float2(0.0f, 0.0f) : buf[c - 1];
  carries[(size_t)bf * NCn + c] = e;
}

// final: O(1) carry lookup + 8-step scan + rotate, bf16 out.
__global__ __launch_bounds__(256) void scan_final(
    const unsigned short* __restrict__ spec, const float* __restrict__ log_decay,
    const float* __restrict__ freq, const float2* __restrict__ carries,
    unsigned short* __restrict__ outH) {
  int tid = threadIdx.x, wid = tid >> 6, lane = tid & 63;
  int chunk = blockIdx.x * 4 + wid;
  int b = chunk >> 9, c = chunk & (NCn - 1);
  int f0 = lane * 4;
  float Are[4], Aim[4], Rre[4], Rim[4], sre[4], sim[4];
  #pragma unroll
  for (int k = 0; k < 4; k++) {
    float dec = 1.0f / (1.0f + expf(-log_decay[f0 + k]));
    float om  = tanhf(freq[f0 + k]) * 0.1f;
    Rre[k] = cosf(om); Rim[k] = sinf(om);
    Are[k] = dec * Rre[k]; Aim[k] = dec * Rim[k];
    float2 s0 = carries[((size_t)(b * 256 + f0 + k)) * NCn + c];
    sre[k] = s0.x; sim[k] = s0.y;
  }
  const unsigned short* u = spec + ((size_t)b * Sn + (size_t)c * CHn) * 512;
  unsigned short* o = outH + ((size_t)b * Sn + (size_t)c * CHn) * 512;
  #pragma unroll
  for (int t = 0; t < CHn; t++) {
    ushort4 ur = *(const ushort4*)(u + (size_t)t * 512 + f0);
    ushort4 ui = *(const ushort4*)(u + (size_t)t * 512 + 256 + f0);
    float urf[4] = {bf2f(ur.x), bf2f(ur.y), bf2f(ur.z), bf2f(ur.w)};
    float uif[4] = {bf2f(ui.x), bf2f(ui.y), bf2f(ui.z), bf2f(ui.w)};
    ushort4 wr, wi;
    unsigned short* wrp = &wr.x;
    unsigned short* wip = &wi.x;
    #pragma unroll
    for (int k = 0; k < 4; k++) {
      float nre = Are[k] * sre[k] - Aim[k] * sim[k] + urf[k];
      float nim = Are[k] * sim[k] + Aim[k] * sre[k] + uif[k];
      sre[k] = nre; sim[k] = nim;
      wrp[k] = f2bf(Rre[k] * sre[k] - Rim[k] * sim[k]);
      wip[k] = f2bf(Rre[k] * sim[k] + Rim[k] * sre[k]);
    }
    *(ushort4*)(o + (size_t)t * 512 + f0) = wr;
    *(ushort4*)(o + (size_t)t * 512 + 256 + f0) = wi;
  }
}

// ---------------------------------------------------------------------------
extern "C" void kernel_launch(void* const* d_in, const int* in_sizes, int n_in,
                              void* d_out, int out_size, void* d_ws, size_t ws_size,
                              hipStream_t stream) {
  (void)in_sizes; (void)n_in; (void)out_size; (void)ws_size;
  const float* x     = (const float*)d_in[0];
  const float* td    = (const float*)d_in[1];
  const float* wspec = (const float*)d_in[2];
  const float* logd  = (const float*)d_in[3];
  const float* freq  = (const float*)d_in[4];
  const float* wfrom = (const float*)d_in[5];
  const float* g1    = (const float*)d_in[6];
  const float* b1ln  = (const float*)d_in[7];
  const float* W1    = (const float*)d_in[8];
  const float* b1    = (const float*)d_in[9];
  const float* W2    = (const float*)d_in[10];
  const float* b2    = (const float*)d_in[11];
  const float* g2    = (const float*)d_in[12];
  const float* b2ln  = (const float*)d_in[13];
  const float* ew    = (const float*)d_in[14];

  char* ws = (char*)d_ws;
  size_t off = 0;
  float* errAcc = (float*)(ws + off);              off += 256;
  unsigned short* wspec_h = (unsigned short*)(ws + off); off += (size_t)512 * 1024 * 2;
  unsigned short* wfrom_h = (unsigned short*)(ws + off); off += (size_t)1024 * 512 * 2;
  unsigned short* w1_h    = (unsigned short*)(ws + off); off += (size_t)1024 * 1024 * 2;
  unsigned short* w2_h    = (unsigned short*)(ws + off); off += (size_t)1024 * 1024 * 2;
  // region A (32MB): xn_h [LN1->G0] -> corr_h [G1->G2] -> h2_h [G3->LN2]
  unsigned short* xn_h   = (unsigned short*)(ws + off);
  unsigned short* corr_h = (unsigned short*)(ws + off);
  unsigned short* h2_h   = (unsigned short*)(ws + off); off += (size_t)Mn * 1024 * 2;
  // region B (32MB): spec bf16 [G0->scan] -> h1_h [G2->G3]
  unsigned short* spec  = (unsigned short*)(ws + off);
  unsigned short* h1_h  = (unsigned short*)(ws + off);  off += (size_t)Mn * 1024 * 2;
  // region C (16MB): so_h [scan_final->G1]
  unsigned short* so_h = (unsigned short*)(ws + off);  off += (size_t)Mn * 512 * 2;
  float2* chunkfin = (float2*)(ws + off);              off += (size_t)Bn * 256 * NCn * 8;
  float2* carries  = (float2*)(ws + off);              off += (size_t)Bn * 256 * NCn * 8;

  float* outCorr = (float*)d_out;
  float* outNP   = outCorr + (size_t)Mn * 1024;
  float* outErr  = outNP + (size_t)Mn * 1024;

  // LN1 + all weight converts + errAcc zero (1M threads, exact cover)
  ln1_conv<<<4096, 256, 0, stream>>>(x, g1, b1ln, xn_h,
                                     wspec, wfrom, W1, W2,
                                     wspec_h, wfrom_h, w1_h, w2_h, errAcc);
  // G0: spectral = xn @ W_spec^T : [16384,1024] x [512,1024]^T -> bf16
  gemm_bt<0><<<dim3(512 / 128, Mn / 128), 256, 0, stream>>>(
      xn_h, wspec_h, 1024, 512, nullptr, spec, nullptr, nullptr, nullptr, nullptr);
  scan_partial<<<512, 256, 0, stream>>>(spec, logd, freq, chunkfin);
  scan_carry<<<1024, 512, 0, stream>>>(logd, freq, chunkfin, carries);
  scan_final<<<512, 256, 0, stream>>>(spec, logd, freq, carries, so_h);
  // G1: bu = so @ W_from^T, fused error/corrected + err^2 reduce
  gemm_bt<1><<<dim3(1024 / 128, Mn / 128), 256, 0, stream>>>(
      so_h, wfrom_h, 512, 1024, outCorr, corr_h, td, nullptr, ew, errAcc);
  // G2: h1 = gelu(corr @ W1^T + b1)
  gemm_bt<2><<<dim3(1024 / 128, Mn / 128), 256, 0, stream>>>(
      corr_h, w1_h, 1024, 1024, nullptr, h1_h, nullptr, b1, nullptr, nullptr);
  // G3: h2 = bf16(h1 @ W2^T + b2)
  gemm_bt<4><<<dim3(1024 / 128, Mn / 128), 256, 0, stream>>>(
      h1_h, w2_h, 1024, 1024, nullptr, h2_h, nullptr, b2, nullptr, nullptr);
  // LN2 (bf16 -> f32 into d_out) + finalize_err
  ln2_err<<<4096, 256, 0, stream>>>(h2_h, g2, b2ln, outNP, errAcc, outErr);
}